// Round 2
// baseline (118.314 us; speedup 1.0000x reference)
//
#include <hip/hip_runtime.h>
#include <math.h>

// DetectionLoss: gather-based exact reimplementation, wave-per-(batch,scale),
// single fused kernel with last-block final reduction.
// pred_p3 (64,11,160,160) f32, pred_p4 (64,11,80,80), pred_p5 (64,11,40,40),
// targets_cls (64,60) i32, targets_box (64,60,4) f32.
// Only B*T=3840 cells/scale are positive -> pure gather problem.
// Collision tie-break: LAST target index wins the box (matches serial scatter
// lowering, verified absmax 0.0); class target is the union of colliding ids.
//
// Structure: 192 blocks = (scale s, batch b), 64 threads = ONE WAVE, no LDS,
// no __syncthreads. Changes this round:
//  - gather of the 10 pred channels HOISTED BEFORE the all-to-all loop: with
//    1 wave/CU there is no TLP, so vmcnt (gather) overlaps lgkmcnt (shfl loop)
//    on the wave's own critical path (~900 cy saved).
//  - all-to-all packs (key<<3)|cls into ONE shfl per iteration.
//  - final reduction fused: workspace counter (zeroed by hipMemsetAsync node),
//    release-ordered partial stores, last block to increment replays the exact
//    same 64-lane-per-scale butterfly as the old detloss_final -> bit-identical
//    result, one fewer dispatch, partials still hot in cache.

#define NCLS 6
#define NT   60
#define NB   64
#define NS   3

__device__ __forceinline__ float iou_fn(float x1, float y1, float w1, float h1,
                                        float x2, float y2, float w2, float h2) {
    // mirror reference arithmetic exactly (compute xyxy, subtract back)
    float x11 = x1 - w1 * 0.5f, y11 = y1 - h1 * 0.5f;
    float x12 = x1 + w1 * 0.5f, y12 = y1 + h1 * 0.5f;
    float x21 = x2 - w2 * 0.5f, y21 = y2 - h2 * 0.5f;
    float x22 = x2 + w2 * 0.5f, y22 = y2 + h2 * 0.5f;
    float iw = fmaxf(fminf(x12, x22) - fmaxf(x11, x21), 0.0f);
    float ih = fmaxf(fminf(y12, y22) - fmaxf(y11, y21), 0.0f);
    float inter = iw * ih;
    float a1 = (x12 - x11) * (y12 - y11);
    float a2 = (x22 - x21) * (y22 - y21);
    return inter / (a1 + a2 - inter + 1e-7f);
}

// grid = NS*NB = 192 blocks, block = 64 (one wave, no barriers anywhere)
__global__ __launch_bounds__(64)
void detloss_fused(const float* __restrict__ p3, const float* __restrict__ p4,
                   const float* __restrict__ p5, const int* __restrict__ tcls,
                   const float* __restrict__ tbox, float* __restrict__ part,
                   unsigned int* __restrict__ counter, float* __restrict__ out) {
    const int bs = blockIdx.x;      // 0..191
    const int s  = bs >> 6;         // scale 0..2
    const int b  = bs & 63;         // batch
    const int t  = threadIdx.x;     // lane 0..63; lanes >= NT are padding
    const bool valid = (t < NT);

    float tx = 0.f, ty = 0.f, tw = 0.f, th = 0.f;
    int   cls = 0;
    int   key = -1 - t;             // distinct negatives: never match a real key
    if (valid) {
        const float4 tb = *reinterpret_cast<const float4*>(tbox + (size_t)(b * NT + t) * 4);
        tx = tb.x; ty = tb.y; tw = tb.z; th = tb.w;
        cls = tcls[b * NT + t];
        const int W = 160 >> s;     // H == W at every scale
        int gx = (int)(tx * (float)W);  // f32 mul then trunc, same as jnp
        int gy = (int)(ty * (float)W);
        gx = min(max(gx, 0), W - 1);
        gy = min(max(gy, 0), W - 1);
        key = (gy << 8) | gx;       // W<=160<256 -> unique encoding
    }

    // --- Hoisted gather: issue all 10 channel loads NOW; results consumed
    // after the shfl loop, so HBM latency overlaps the ds_bpermute chain.
    const int W  = 160 >> s;
    const int HW = W * W;
    const float* pred = (s == 0) ? p3 : ((s == 1) ? p4 : p5);
    float ch[10];
    #pragma unroll
    for (int c = 0; c < 10; ++c) ch[c] = 0.0f;
    if (valid) {
        const int gx = key & 255, gy = key >> 8;
        const float* cell = pred + (size_t)b * 11 * HW + (size_t)gy * W + gx;
        #pragma unroll
        for (int c = 0; c < NCLS; ++c) ch[c] = cell[(size_t)c * HW];
        // box channels are 7..10 (channel 6 skipped by NC+1:)
        #pragma unroll
        for (int c = 0; c < 4; ++c) ch[NCLS + c] = cell[(size_t)(7 + c) * HW];
    }

    // --- All-to-all within the wave, one packed shfl per iteration:
    // pk = (key<<3)|cls; key<2^16 so pk fits easily; invalid lanes keep
    // distinct negative keys ((-1-t)<<3, arithmetic >>3 recovers -1-t).
    const int pk = (key << 3) | cls;
    int  mask   = 0;
    bool winner = valid;
    for (int t2 = 0; t2 < NT; ++t2) {
        const int p2 = __shfl(pk, t2);
        if ((p2 >> 3) == key) {
            mask |= 1 << (p2 & 7);
            if (t2 > t) winner = false;   // last index wins the cell
        }
    }

    float n_pos = 0.f, bce_s = 0.f, iou_s = 0.f, inn_s = 0.f;
    if (winner) {
        // BCE over the 6 class channels at this cell
        float bce = 0.0f;
        #pragma unroll
        for (int c = 0; c < NCLS; ++c) {
            float xv = ch[c];
            float tv = (float)((mask >> c) & 1);
            bce += fmaxf(xv, 0.0f) - xv * tv + log1pf(expf(-fabsf(xv)));
        }
        float px = ch[6], py = ch[7], pw = ch[8], ph = ch[9];

        n_pos = 1.0f;
        bce_s = bce;
        iou_s = 1.0f - iou_fn(px, py, pw, ph, tx, ty, tw, th);
        inn_s = 1.0f - iou_fn(px, py, pw * 0.7f, ph * 0.7f,
                              tx, ty, tw * 0.7f, th * 0.7f);
    }

    // 64-lane butterfly reduction (non-winners/padding contribute 0)
    #pragma unroll
    for (int off = 32; off > 0; off >>= 1) {
        n_pos += __shfl_xor(n_pos, off);
        bce_s += __shfl_xor(bce_s, off);
        iou_s += __shfl_xor(iou_s, off);
        inn_s += __shfl_xor(inn_s, off);
    }

    // --- Publish partial (device-scope atomic stores: visible across XCDs),
    // then bump the done-counter with release ordering.
    int last = 0;
    if (t == 0) {
        float vals[4] = {n_pos, bce_s, iou_s, inn_s};
        #pragma unroll
        for (int j = 0; j < 4; ++j)
            __hip_atomic_store(&part[(size_t)bs * 4 + j], vals[j],
                               __ATOMIC_RELAXED, __HIP_MEMORY_SCOPE_AGENT);
        unsigned int old = __hip_atomic_fetch_add(counter, 1u,
                               __ATOMIC_ACQ_REL, __HIP_MEMORY_SCOPE_AGENT);
        last = (old == NS * NB - 1) ? 1 : 0;
    }
    last = __shfl(last, 0);

    // --- Last block replays the EXACT same per-scale 64-lane butterfly the
    // old detloss_final used -> bit-identical sums. No spinning: only the
    // final incrementer runs this, so no deadlock under any scheduling.
    if (last) {
        float n[NS], c[NS], io[NS], in_[NS];
        #pragma unroll
        for (int sc = 0; sc < NS; ++sc) {
            const size_t base = (size_t)(sc * NB + t) * 4;
            n[sc]   = __hip_atomic_load(&part[base + 0], __ATOMIC_RELAXED, __HIP_MEMORY_SCOPE_AGENT);
            c[sc]   = __hip_atomic_load(&part[base + 1], __ATOMIC_RELAXED, __HIP_MEMORY_SCOPE_AGENT);
            io[sc]  = __hip_atomic_load(&part[base + 2], __ATOMIC_RELAXED, __HIP_MEMORY_SCOPE_AGENT);
            in_[sc] = __hip_atomic_load(&part[base + 3], __ATOMIC_RELAXED, __HIP_MEMORY_SCOPE_AGENT);
        }
        #pragma unroll
        for (int off = 32; off > 0; off >>= 1) {
            #pragma unroll
            for (int sc = 0; sc < NS; ++sc) {
                n[sc]   += __shfl_xor(n[sc], off);
                c[sc]   += __shfl_xor(c[sc], off);
                io[sc]  += __shfl_xor(io[sc], off);
                in_[sc] += __shfl_xor(in_[sc], off);
            }
        }
        if (t == 0) {
            float cls_total = 0.0f, box_total = 0.0f;
            #pragma unroll
            for (int sc = 0; sc < NS; ++sc) {
                float denom      = n[sc] + 1e-8f;
                float cls_loss   = c[sc] / denom;
                float iou_term   = io[sc] / denom;
                float inner_term = in_[sc] / denom;
                float inner_iou  = 0.5f * iou_term + 0.5f * inner_term;  // (1-INNER_W), INNER_W
                float box_loss   = 0.5f * iou_term + 0.5f * inner_iou;
                cls_total += cls_loss;
                box_total += box_loss;
            }
            cls_total *= (1.0f / 3.0f);
            box_total *= (1.0f / 3.0f);
            out[0] = 0.5f * cls_total + 7.5f * box_total;  // CLS_W, BOX_W
            out[1] = cls_total;
            out[2] = box_total;
        }
    }
}

extern "C" void kernel_launch(void* const* d_in, const int* in_sizes, int n_in,
                              void* d_out, int out_size, void* d_ws, size_t ws_size,
                              hipStream_t stream) {
    const float* p3   = (const float*)d_in[0];
    const float* p4   = (const float*)d_in[1];
    const float* p5   = (const float*)d_in[2];
    const int*   tcls = (const int*)d_in[3];
    const float* tbox = (const float*)d_in[4];
    float* out  = (float*)d_out;
    float* part = (float*)d_ws;                          // NS*NB*4 floats = 3072 B
    unsigned int* counter = (unsigned int*)((char*)d_ws + NS * NB * 4 * sizeof(float));

    // zero the done-counter each replay (workspace is poisoned by the harness)
    hipMemsetAsync(counter, 0, sizeof(unsigned int), stream);
    detloss_fused<<<NS * NB, 64, 0, stream>>>(p3, p4, p5, tcls, tbox, part, counter, out);
}

// Round 3
// 115.398 us; speedup vs baseline: 1.0253x; 1.0253x over previous
//
#include <hip/hip_runtime.h>
#include <math.h>

// DetectionLoss: gather-based exact reimplementation, wave-per-(batch,scale).
// pred_p3 (64,11,160,160) f32, pred_p4 (64,11,80,80), pred_p5 (64,11,40,40),
// targets_cls (64,60) i32, targets_box (64,60,4) f32.
// Only B*T=3840 cells/scale are positive -> pure gather problem.
// Collision tie-break: LAST target index wins the box (matches serial scatter
// lowering, verified absmax 0.0); class target is the union of colliding ids.
//
// R3 = R1 two-kernel skeleton (best measured: 116.0 us) + R2's orthogonal
// improvements, fusion reverted (R2 post-mortem: memset node == fillBuffer
// dispatch, so fusion saved nothing and added an acq-rel atomic chain +
// cross-XCD agent-scope loads on the last block's critical path; -2.3 us).
//  - 192 blocks = (scale, batch), 64 threads = ONE WAVE, no LDS, no barriers.
//  - 10-channel gather HOISTED before the all-to-all shfl loop: 1 wave/CU has
//    no TLP, so the ~900 cy cold-gather vmcnt chain overlaps the lgkmcnt
//    shfl chain instead of serializing after it.
//  - all-to-all packs (key<<3)|cls into ONE shfl per iteration.
//  - final kernel: one wave; lane t owns batch t, butterfly per scale ->
//    bit-identical reduction tree to R1.

#define NCLS 6
#define NT   60
#define NB   64
#define NS   3

__device__ __forceinline__ float iou_fn(float x1, float y1, float w1, float h1,
                                        float x2, float y2, float w2, float h2) {
    // mirror reference arithmetic exactly (compute xyxy, subtract back)
    float x11 = x1 - w1 * 0.5f, y11 = y1 - h1 * 0.5f;
    float x12 = x1 + w1 * 0.5f, y12 = y1 + h1 * 0.5f;
    float x21 = x2 - w2 * 0.5f, y21 = y2 - h2 * 0.5f;
    float x22 = x2 + w2 * 0.5f, y22 = y2 + h2 * 0.5f;
    float iw = fmaxf(fminf(x12, x22) - fmaxf(x11, x21), 0.0f);
    float ih = fmaxf(fminf(y12, y22) - fmaxf(y11, y21), 0.0f);
    float inter = iw * ih;
    float a1 = (x12 - x11) * (y12 - y11);
    float a2 = (x22 - x21) * (y22 - y21);
    return inter / (a1 + a2 - inter + 1e-7f);
}

// grid = NS*NB = 192 blocks, block = 64 (one wave, no barriers anywhere)
__global__ __launch_bounds__(64)
void detloss_main(const float* __restrict__ p3, const float* __restrict__ p4,
                  const float* __restrict__ p5, const int* __restrict__ tcls,
                  const float* __restrict__ tbox, float* __restrict__ part) {
    const int bs = blockIdx.x;      // 0..191
    const int s  = bs >> 6;         // scale 0..2
    const int b  = bs & 63;         // batch
    const int t  = threadIdx.x;     // lane 0..63; lanes >= NT are padding
    const bool valid = (t < NT);

    float tx = 0.f, ty = 0.f, tw = 0.f, th = 0.f;
    int   cls = 0;
    int   key = -1 - t;             // distinct negatives: never match a real key
    if (valid) {
        const float4 tb = *reinterpret_cast<const float4*>(tbox + (size_t)(b * NT + t) * 4);
        tx = tb.x; ty = tb.y; tw = tb.z; th = tb.w;
        cls = tcls[b * NT + t];
        const int W = 160 >> s;     // H == W at every scale
        int gx = (int)(tx * (float)W);  // f32 mul then trunc, same as jnp
        int gy = (int)(ty * (float)W);
        gx = min(max(gx, 0), W - 1);
        gy = min(max(gy, 0), W - 1);
        key = (gy << 8) | gx;       // W<=160<256 -> unique encoding
    }

    // --- Hoisted gather: issue all 10 channel loads NOW; results consumed
    // after the shfl loop, so HBM latency overlaps the shfl chain.
    const int W  = 160 >> s;
    const int HW = W * W;
    const float* pred = (s == 0) ? p3 : ((s == 1) ? p4 : p5);
    float ch[10];
    #pragma unroll
    for (int c = 0; c < 10; ++c) ch[c] = 0.0f;
    if (valid) {
        const int gx = key & 255, gy = key >> 8;
        const float* cell = pred + (size_t)b * 11 * HW + (size_t)gy * W + gx;
        #pragma unroll
        for (int c = 0; c < NCLS; ++c) ch[c] = cell[(size_t)c * HW];
        // box channels are 7..10 (channel 6 skipped by NC+1:)
        #pragma unroll
        for (int c = 0; c < 4; ++c) ch[NCLS + c] = cell[(size_t)(7 + c) * HW];
    }

    // --- All-to-all within the wave, one packed shfl per iteration:
    // pk = (key<<3)|cls; key<2^16 so pk fits easily; invalid lanes keep
    // distinct negative keys ((-1-t)<<3, arithmetic >>3 recovers -1-t).
    const int pk = (key << 3) | cls;
    int  mask   = 0;
    bool winner = valid;
    for (int t2 = 0; t2 < NT; ++t2) {
        const int p2 = __shfl(pk, t2);
        if ((p2 >> 3) == key) {
            mask |= 1 << (p2 & 7);
            if (t2 > t) winner = false;   // last index wins the cell
        }
    }

    float n_pos = 0.f, bce_s = 0.f, iou_s = 0.f, inn_s = 0.f;
    if (winner) {
        // BCE over the 6 class channels at this cell
        float bce = 0.0f;
        #pragma unroll
        for (int c = 0; c < NCLS; ++c) {
            float xv = ch[c];
            float tv = (float)((mask >> c) & 1);
            bce += fmaxf(xv, 0.0f) - xv * tv + log1pf(expf(-fabsf(xv)));
        }
        float px = ch[6], py = ch[7], pw = ch[8], ph = ch[9];

        n_pos = 1.0f;
        bce_s = bce;
        iou_s = 1.0f - iou_fn(px, py, pw, ph, tx, ty, tw, th);
        inn_s = 1.0f - iou_fn(px, py, pw * 0.7f, ph * 0.7f,
                              tx, ty, tw * 0.7f, th * 0.7f);
    }

    // 64-lane butterfly reduction (non-winners/padding contribute 0)
    #pragma unroll
    for (int off = 32; off > 0; off >>= 1) {
        n_pos += __shfl_xor(n_pos, off);
        bce_s += __shfl_xor(bce_s, off);
        iou_s += __shfl_xor(iou_s, off);
        inn_s += __shfl_xor(inn_s, off);
    }

    if (t == 0) {
        float4 o = make_float4(n_pos, bce_s, iou_s, inn_s);
        *reinterpret_cast<float4*>(part + (size_t)bs * 4) = o;  // every slot written: poison-safe
    }
}

// 1 block x 64 threads (one wave): lane t owns batch t; per-scale butterfly
// is the same 64-lane tree as before -> bit-identical sums.
__global__ __launch_bounds__(64)
void detloss_final(const float* __restrict__ part, float* __restrict__ out) {
    const int t = threadIdx.x;

    float n[NS], c[NS], io[NS], in_[NS];
    #pragma unroll
    for (int sc = 0; sc < NS; ++sc) {
        const float4 v = *reinterpret_cast<const float4*>(part + (size_t)(sc * NB + t) * 4);
        n[sc] = v.x; c[sc] = v.y; io[sc] = v.z; in_[sc] = v.w;
    }
    #pragma unroll
    for (int off = 32; off > 0; off >>= 1) {
        #pragma unroll
        for (int sc = 0; sc < NS; ++sc) {
            n[sc]   += __shfl_xor(n[sc], off);
            c[sc]   += __shfl_xor(c[sc], off);
            io[sc]  += __shfl_xor(io[sc], off);
            in_[sc] += __shfl_xor(in_[sc], off);
        }
    }
    if (t == 0) {
        float cls_total = 0.0f, box_total = 0.0f;
        #pragma unroll
        for (int sc = 0; sc < NS; ++sc) {
            float denom      = n[sc] + 1e-8f;
            float cls_loss   = c[sc] / denom;
            float iou_term   = io[sc] / denom;
            float inner_term = in_[sc] / denom;
            float inner_iou  = 0.5f * iou_term + 0.5f * inner_term;  // (1-INNER_W), INNER_W
            float box_loss   = 0.5f * iou_term + 0.5f * inner_iou;
            cls_total += cls_loss;
            box_total += box_loss;
        }
        cls_total *= (1.0f / 3.0f);
        box_total *= (1.0f / 3.0f);
        out[0] = 0.5f * cls_total + 7.5f * box_total;  // CLS_W, BOX_W
        out[1] = cls_total;
        out[2] = box_total;
    }
}

extern "C" void kernel_launch(void* const* d_in, const int* in_sizes, int n_in,
                              void* d_out, int out_size, void* d_ws, size_t ws_size,
                              hipStream_t stream) {
    const float* p3   = (const float*)d_in[0];
    const float* p4   = (const float*)d_in[1];
    const float* p5   = (const float*)d_in[2];
    const int*   tcls = (const int*)d_in[3];
    const float* tbox = (const float*)d_in[4];
    float* out  = (float*)d_out;
    float* part = (float*)d_ws;  // NS*NB*4 floats = 3 KB

    detloss_main<<<NS * NB, 64, 0, stream>>>(p3, p4, p5, tcls, tbox, part);
    detloss_final<<<1, 64, 0, stream>>>(part, out);
}